// Round 6
// baseline (173.620 us; speedup 1.0000x reference)
//
#include <hip/hip_runtime.h>
#include <cmath>

#define NN 20000
#define DD 256
#define KK 16
#define LDROW 1024   // C3 row: [s 0..255][ut interleaved 256..767][t 768..1023]

typedef __attribute__((ext_vector_type(8))) short short8;
typedef __attribute__((ext_vector_type(4))) float f32x4;
typedef unsigned int u32;
typedef unsigned short bfu;

__device__ __forceinline__ float b2f(bfu u) {
  union { u32 i; float f; } v; v.i = ((u32)u) << 16; return v.f;
}
__device__ __forceinline__ bfu f2b(float f) {
  u32 u = __float_as_uint(f);
  u = (u + 0x7fff + ((u >> 16) & 1)) >> 16;
  return (bfu)u;
}
__device__ __forceinline__ float wave_sum(float v) {
#pragma unroll
  for (int m = 32; m; m >>= 1) v += __shfl_xor(v, m, 64);
  return v;
}
__device__ __forceinline__ void gl_lds16(const void* g, void* l) {
  __builtin_amdgcn_global_load_lds((const __attribute__((address_space(1))) u32*)g,
                                   (__attribute__((address_space(3))) u32*)l, 16, 0, 0);
}
template<int N> __device__ __forceinline__ void wait_vm() {
  asm volatile("s_waitcnt vmcnt(%0)" :: "i"(N) : "memory");
}
__device__ __forceinline__ void bar() {
  __builtin_amdgcn_sched_barrier(0);
  __builtin_amdgcn_s_barrier();
  __builtin_amdgcn_sched_barrier(0);
}

// -------- prep: LayerNorm (blocks 0..4999, t stored twice: contiguous for GEMM-A,
// interleaved for gather) + weight f32->bf16 (blocks 5000+) ----------------------
__global__ __launch_bounds__(256) void prep_kernel(
    const float* __restrict__ x, const float* __restrict__ g,
    const float* __restrict__ b, const float* __restrict__ Wself,
    const float* __restrict__ Wnei, const float* __restrict__ Wred,
    bfu* __restrict__ C3, bfu* __restrict__ Wcat, bfu* __restrict__ Wredb) {
  int bid = blockIdx.x;
  if (bid < 5000) {
    int lane = threadIdx.x & 63;
    int row = (bid << 2) + (threadIdx.x >> 6);
    float4 v = ((const float4*)(x + (size_t)row * DD))[lane];
    float mean = wave_sum(v.x + v.y + v.z + v.w) * (1.0f / 256.0f);
    float4 d = make_float4(v.x - mean, v.y - mean, v.z - mean, v.w - mean);
    float var = wave_sum(d.x * d.x + d.y * d.y + d.z * d.z + d.w * d.w) * (1.0f / 256.0f);
    float rstd = 1.0f / sqrtf(var + 1e-5f);
    float4 g4 = ((const float4*)g)[lane];
    float4 b4 = ((const float4*)b)[lane];
    ushort4 ov;
    ov.x = f2b(d.x * rstd * g4.x + b4.x);
    ov.y = f2b(d.y * rstd * g4.y + b4.y);
    ov.z = f2b(d.z * rstd * g4.z + b4.z);
    ov.w = f2b(d.w * rstd * g4.w + b4.w);
    bfu* rowp = C3 + (size_t)row * LDROW;
    *(ushort4*)(rowp + 768 + (lane << 2)) = ov;          // contiguous (GEMM A)
    *(ushort4*)(rowp + 256 + (lane << 3) + 4) = ov;      // interleaved t-half
  } else {
    int idx = (bid - 5000) * 256 + threadIdx.x;
    if (idx < 65536) Wcat[idx] = f2b(Wself[idx]);
    else if (idx < 131072) Wcat[idx] = f2b(Wnei[idx - 65536]);
    else if (idx < 147456) Wredb[idx - 131072] = f2b(Wred[idx - 131072]);
  }
}

// -------- bf16 MFMA GEMM, counted-vmcnt pipeline (loads never drained mid-loop) --
// C[m, nbase+n] = A[m,:256] . W[nbase+n,:] + bias. Swapped-operand MFMA so each
// lane holds 4 consecutive output cols. K=256 fixed (4 steps of BK=64).
template<int MT, int NT, int LDA, bool FINAL>
__global__ __launch_bounds__(256) void gemm_kernel(
    const bfu* __restrict__ A, const bfu* __restrict__ Bw,
    const float* __restrict__ bias0, const float* __restrict__ bias1,
    bfu* __restrict__ C3out, float* __restrict__ Fout, int M) {
  constexpr int WM = MT / 2, WN = NT / 2, FM = WM / 16, FN = WN / 16;
  constexpr int AIT = MT * 8 / 256, BIT = NT * 8 / 256;
  constexpr int VM = (MT + NT) / 32;          // loads per thread per STAGE
  __shared__ bfu smA[2][MT * 64];
  __shared__ bfu smB[2][NT * 64];
  int tid = threadIdx.x, lane = tid & 63, wid = tid >> 6;
  int m0 = blockIdx.x * MT;
  int nbase = blockIdx.y * NT;
  const bfu* Bt = Bw + (size_t)nbase * 256;
  int wr = wid >> 1, wc = wid & 1;
  int lr = lane & 15, lk = lane >> 4;

  f32x4 acc[FM][FN];
#pragma unroll
  for (int i = 0; i < FM; ++i)
#pragma unroll
    for (int j = 0; j < FN; ++j) acc[i][j] = (f32x4){0.f, 0.f, 0.f, 0.f};

#define STAGE(buf, kc)                                                          \
  {                                                                             \
    _Pragma("unroll") for (int i = 0; i < AIT; ++i) {                           \
      int p = tid + 256 * i; int row = p >> 3; int c = (p & 7) ^ (row & 7);     \
      gl_lds16(A + (size_t)(m0 + row) * LDA + (kc) + c * 8, &smA[buf][p * 8]);  \
    }                                                                           \
    _Pragma("unroll") for (int i = 0; i < BIT; ++i) {                           \
      int p = tid + 256 * i; int row = p >> 3; int c = (p & 7) ^ (row & 7);     \
      gl_lds16(Bt + (size_t)row * 256 + (kc) + c * 8, &smB[buf][p * 8]);        \
    }                                                                           \
  }

#define COMPUTE(buf)                                                            \
  {                                                                             \
    _Pragma("unroll") for (int h = 0; h < 2; ++h) {                             \
      short8 af[FM], bfr[FN];                                                   \
      int cc = h * 4 + lk;                                                      \
      _Pragma("unroll") for (int fm = 0; fm < FM; ++fm) {                       \
        int row = wr * WM + fm * 16 + lr;                                       \
        af[fm] = *(const short8*)&smA[buf][row * 64 + ((cc ^ (row & 7)) << 3)]; \
      }                                                                         \
      _Pragma("unroll") for (int fn = 0; fn < FN; ++fn) {                       \
        int row = wc * WN + fn * 16 + lr;                                       \
        bfr[fn] = *(const short8*)&smB[buf][row * 64 + ((cc ^ (row & 7)) << 3)];\
      }                                                                         \
      _Pragma("unroll") for (int fm = 0; fm < FM; ++fm)                         \
        _Pragma("unroll") for (int fn = 0; fn < FN; ++fn)                       \
          acc[fm][fn] = __builtin_amdgcn_mfma_f32_16x16x32_bf16(                \
              bfr[fn], af[fm], acc[fm][fn], 0, 0, 0);                           \
    }                                                                           \
  }

  // counted-vmcnt pipeline: loads for tile k+1 stay in flight across COMPUTE(k).
  STAGE(0, 0);                    // VM loads   (buf0)
  STAGE(1, 64);                   // VM loads   (buf1)  -> 2*VM outstanding
  wait_vm<VM>(); bar();           // buf0 landed (all waves)
  COMPUTE(0);
  bar();                          // all waves done reading buf0
  STAGE(0, 128);                  // -> buf1 + buf0' outstanding
  wait_vm<VM>(); bar();           // buf1 landed
  COMPUTE(1);
  bar();                          // all waves done reading buf1
  STAGE(1, 192);                  // -> buf0' + buf1' outstanding
  wait_vm<VM>(); bar();           // buf0' landed
  COMPUTE(0);
  wait_vm<0>(); bar();            // buf1' landed (all waves)
  COMPUTE(1);
#undef STAGE
#undef COMPUTE

  const float* bias = (nbase < 256) ? (bias0 + nbase) : (bias1 + (nbase - 256));
#pragma unroll
  for (int fm = 0; fm < FM; ++fm) {
    int m = m0 + wr * WM + fm * 16 + lr;
    if (m >= M) continue;
#pragma unroll
    for (int fn = 0; fn < FN; ++fn) {
      int lc = wc * WN + fn * 16 + lk * 4;
      float4 bv = *(const float4*)(bias + lc);
      float o0 = acc[fm][fn][0] + bv.x;
      float o1 = acc[fm][fn][1] + bv.y;
      float o2 = acc[fm][fn][2] + bv.z;
      float o3 = acc[fm][fn][3] + bv.w;
      if (FINAL) {
        o0 = (o0 > 0.f) ? o0 : 0.01f * o0; o0 = (o0 > 0.f) ? o0 : 0.01f * o0;
        o1 = (o1 > 0.f) ? o1 : 0.01f * o1; o1 = (o1 > 0.f) ? o1 : 0.01f * o1;
        o2 = (o2 > 0.f) ? o2 : 0.01f * o2; o2 = (o2 > 0.f) ? o2 : 0.01f * o2;
        o3 = (o3 > 0.f) ? o3 : 0.01f * o3; o3 = (o3 > 0.f) ? o3 : 0.01f * o3;
        *(float4*)(Fout + (size_t)m * NT + nbase + lc) = make_float4(o0, o1, o2, o3);
      } else {
        ushort4 ov; ov.x = f2b(o0); ov.y = f2b(o1); ov.z = f2b(o2); ov.w = f2b(o3);
        if (nbase < 256) {   // s: contiguous
          *(ushort4*)(C3out + (size_t)m * LDROW + nbase + lc) = ov;
        } else {             // u: interleaved chunk (cols are a 4-aligned quad)
          int f = nbase - 256 + lc;
          *(ushort4*)(C3out + (size_t)m * LDROW + 256 + ((f >> 2) << 3)) = ov;
        }
      }
    }
  }
}

// -------- gather + softmax(17) + threshold + context; one 16B load per neighbor --
__global__ __launch_bounds__(256) void gather_kernel(
    const bfu* __restrict__ C3, const float* __restrict__ coords,
    const int* __restrict__ col, const float* __restrict__ bmix,
    bfu* __restrict__ ctx) {
  const float L2E = 1.4426950408889634f;
  int lane = threadIdx.x & 63;
  int i = (blockIdx.x << 2) + (threadIdx.x >> 6);
  float beta = bmix[0];

  int ck = col[i * KK + (lane & 15)];
  float2 ci = ((const float2*)coords)[i];
  float2 cn = ((const float2*)coords)[ck];
  float dx = ci.x - cn.x, dy = ci.y - cn.y;
  float dwv = exp2f((-2.0f * L2E / (50.0f + 1e-8f)) * sqrtf(dx * dx + dy * dy)) * L2E;

  int d = lane << 2;
  const bfu* rowi = C3 + (size_t)i * LDROW;
  ushort4 sv = *(const ushort4*)(rowi + d);
  short8 self8 = *(const short8*)(rowi + 256 + (lane << 3));   // [u_self|t_self]
  float4 e0 = make_float4(exp2f(L2E * b2f(sv.x)), exp2f(L2E * b2f(sv.y)),
                          exp2f(L2E * b2f(sv.z)), exp2f(L2E * b2f(sv.w)));
  float4 Z = e0;
  float4 ef[KK];
  ushort4 tn[KK];
#pragma unroll
  for (int k = 0; k < KK; ++k) {
    int cc = __shfl(ck, k, 64);
    float w = __shfl(dwv, k, 64);
    short8 v = *(const short8*)(C3 + (size_t)cc * LDROW + 256 + (lane << 3));
    tn[k].x = (bfu)v[4]; tn[k].y = (bfu)v[5]; tn[k].z = (bfu)v[6]; tn[k].w = (bfu)v[7];
    float4 e = make_float4(exp2f(w * b2f((bfu)v[0])), exp2f(w * b2f((bfu)v[1])),
                           exp2f(w * b2f((bfu)v[2])), exp2f(w * b2f((bfu)v[3])));
    ef[k] = e;
    Z.x += e.x; Z.y += e.y; Z.z += e.z; Z.w += e.w;
  }
  // threshold on weight e/Z >= 0.01  <=>  e >= 0.01*Z (weights positive)
  float4 thr = make_float4(0.01f * Z.x, 0.01f * Z.y, 0.01f * Z.z, 0.01f * Z.w);
  float ob = 1.0f - beta;
  float4 ns = make_float4(0.f, 0.f, 0.f, 0.f);
#pragma unroll
  for (int k = 0; k < KK; ++k) {
    float ex = (ef[k].x >= thr.x) ? ef[k].x : 0.f;
    float ey = (ef[k].y >= thr.y) ? ef[k].y : 0.f;
    float ez = (ef[k].z >= thr.z) ? ef[k].z : 0.f;
    float ew = (ef[k].w >= thr.w) ? ef[k].w : 0.f;
    ns.x += ex * b2f(tn[k].x); ns.y += ey * b2f(tn[k].y);
    ns.z += ez * b2f(tn[k].z); ns.w += ew * b2f(tn[k].w);
  }
  float s0x = (e0.x >= thr.x) ? e0.x : 0.f;
  float s0y = (e0.y >= thr.y) ? e0.y : 0.f;
  float s0z = (e0.z >= thr.z) ? e0.z : 0.f;
  float s0w = (e0.w >= thr.w) ? e0.w : 0.f;
  ushort4 ov;
  ov.x = f2b((beta * s0x * b2f((bfu)self8[4]) + ob * ns.x) / Z.x);
  ov.y = f2b((beta * s0y * b2f((bfu)self8[5]) + ob * ns.y) / Z.y);
  ov.z = f2b((beta * s0z * b2f((bfu)self8[6]) + ob * ns.z) / Z.z);
  ov.w = f2b((beta * s0w * b2f((bfu)self8[7]) + ob * ns.w) / Z.w);
  *(ushort4*)(ctx + (size_t)i * DD + d) = ov;
}

extern "C" void kernel_launch(void* const* d_in, const int* in_sizes, int n_in,
                              void* d_out, int out_size, void* d_ws, size_t ws_size,
                              hipStream_t stream) {
  (void)in_sizes; (void)n_in; (void)out_size; (void)ws_size;
  const float* x       = (const float*)d_in[0];
  const float* coords  = (const float*)d_in[1];
  const float* gamma   = (const float*)d_in[2];
  const float* beta_ln = (const float*)d_in[3];
  const float* W_self  = (const float*)d_in[4];
  const float* b_self  = (const float*)d_in[5];
  const float* W_nei   = (const float*)d_in[6];
  const float* b_nei   = (const float*)d_in[7];
  const float* W_red   = (const float*)d_in[8];
  const float* b_red   = (const float*)d_in[9];
  const float* bmix    = (const float*)d_in[10];
  const int*   edge    = (const int*)d_in[11];
  const int*   col     = edge + (size_t)NN * KK;

  // workspace (20096 rows so last-tile OOB reads stay in-bounds & harmless)
  bfu* C3    = (bfu*)d_ws;                              // 20096*1024*2 = 41,156,608
  bfu* ctx   = (bfu*)((char*)d_ws + 41156608);          // 20096*256*2  = 10,289,152
  bfu* Wcat  = (bfu*)((char*)d_ws + 51445760);          // 512*256*2    =    262,144
  bfu* Wredb = (bfu*)((char*)d_ws + 51707904);          //  64*256*2    =     32,768

  prep_kernel<<<5576, 256, 0, stream>>>(x, gamma, beta_ln, W_self, W_nei, W_red,
                                        C3, Wcat, Wredb);
  gemm_kernel<128, 128, LDROW, false><<<dim3(157, 4), 256, 0, stream>>>(
      C3 + 768, Wcat, b_self, b_nei, C3, nullptr, NN);
  gather_kernel<<<5000, 256, 0, stream>>>(C3, coords, col, bmix, ctx);
  gemm_kernel<64, 64, 256, true><<<dim3(313, 1), 256, 0, stream>>>(
      ctx, Wredb, b_red, b_red, nullptr, (float*)d_out, NN);
}

// Round 13
// 160.859 us; speedup vs baseline: 1.0793x; 1.0793x over previous
//
#include <hip/hip_runtime.h>
#include <cmath>

#define NN 20000
#define DD 256
#define KK 16
#define LDC3 768   // C3 row: [s 0..255][u 256..511][t 512..767]

typedef __attribute__((ext_vector_type(8))) short short8;
typedef __attribute__((ext_vector_type(4))) float f32x4;
typedef unsigned int u32;
typedef unsigned short bfu;

__device__ __forceinline__ float b2f(bfu u) {
  union { u32 i; float f; } v; v.i = ((u32)u) << 16; return v.f;
}
__device__ __forceinline__ bfu f2b(float f) {
  u32 u = __float_as_uint(f);
  u = (u + 0x7fff + ((u >> 16) & 1)) >> 16;
  return (bfu)u;
}
__device__ __forceinline__ float wave_sum(float v) {
#pragma unroll
  for (int m = 32; m; m >>= 1) v += __shfl_xor(v, m, 64);
  return v;
}
__device__ __forceinline__ void gl_lds16(const void* g, void* l) {
  __builtin_amdgcn_global_load_lds((const __attribute__((address_space(1))) u32*)g,
                                   (__attribute__((address_space(3))) u32*)l, 16, 0, 0);
}
// raw v_exp_f32 / v_rcp_f32 (inputs bounded; avoids libm fixup sequences)
__device__ __forceinline__ float fexp2(float x) { return __builtin_amdgcn_exp2f(x); }
__device__ __forceinline__ float frcp(float x)  { return __builtin_amdgcn_rcpf(x); }

// -------- prep: LayerNorm (blocks 0..4999) + weight f32->bf16 (blocks 5000+) -----
__global__ __launch_bounds__(256) void prep_kernel(
    const float* __restrict__ x, const float* __restrict__ g,
    const float* __restrict__ b, const float* __restrict__ Wself,
    const float* __restrict__ Wnei, const float* __restrict__ Wred,
    bfu* __restrict__ C3, bfu* __restrict__ Wcat, bfu* __restrict__ Wredb) {
  int bid = blockIdx.x;
  if (bid < 5000) {
    int lane = threadIdx.x & 63;
    int row = (bid << 2) + (threadIdx.x >> 6);
    float4 v = ((const float4*)(x + (size_t)row * DD))[lane];
    float mean = wave_sum(v.x + v.y + v.z + v.w) * (1.0f / 256.0f);
    float4 d = make_float4(v.x - mean, v.y - mean, v.z - mean, v.w - mean);
    float var = wave_sum(d.x * d.x + d.y * d.y + d.z * d.z + d.w * d.w) * (1.0f / 256.0f);
    float rstd = 1.0f / sqrtf(var + 1e-5f);
    float4 g4 = ((const float4*)g)[lane];
    float4 b4 = ((const float4*)b)[lane];
    ushort4 ov;
    ov.x = f2b(d.x * rstd * g4.x + b4.x);
    ov.y = f2b(d.y * rstd * g4.y + b4.y);
    ov.z = f2b(d.z * rstd * g4.z + b4.z);
    ov.w = f2b(d.w * rstd * g4.w + b4.w);
    *(ushort4*)(C3 + (size_t)row * LDC3 + 512 + (lane << 2)) = ov;
  } else {
    int idx = (bid - 5000) * 256 + threadIdx.x;
    if (idx < 65536) Wcat[idx] = f2b(Wself[idx]);
    else if (idx < 131072) Wcat[idx] = f2b(Wnei[idx - 65536]);
    else if (idx < 147456) Wredb[idx - 131072] = f2b(Wred[idx - 131072]);
  }
}

// -------- bf16 MFMA GEMM (r5 known-good): 128x128 tile, __syncthreads dbuf ------
__global__ __launch_bounds__(256) void gemm_kernel(
    const bfu* __restrict__ A, const bfu* __restrict__ Bw,
    const float* __restrict__ bias0, const float* __restrict__ bias1,
    bfu* __restrict__ Cout, int M) {
  __shared__ bfu smA[2][128 * 64];
  __shared__ bfu smB[2][128 * 64];
  int tid = threadIdx.x, lane = tid & 63, wid = tid >> 6;
  int m0 = blockIdx.x * 128;
  int nbase = blockIdx.y * 128;
  const bfu* Bt = Bw + (size_t)nbase * 256;
  int wr = wid >> 1, wc = wid & 1;
  int lr = lane & 15, lk = lane >> 4;

  f32x4 acc[4][4];
#pragma unroll
  for (int i = 0; i < 4; ++i)
#pragma unroll
    for (int j = 0; j < 4; ++j) acc[i][j] = (f32x4){0.f, 0.f, 0.f, 0.f};

#define STAGE(buf, kc)                                                           \
  {                                                                              \
    _Pragma("unroll") for (int i = 0; i < 4; ++i) {                              \
      int p = tid + 256 * i; int row = p >> 3; int c = (p & 7) ^ (row & 7);      \
      gl_lds16(A + (size_t)(m0 + row) * LDC3 + (kc) + c * 8, &smA[buf][p * 8]);  \
    }                                                                            \
    _Pragma("unroll") for (int i = 0; i < 4; ++i) {                              \
      int p = tid + 256 * i; int row = p >> 3; int c = (p & 7) ^ (row & 7);      \
      gl_lds16(Bt + (size_t)row * 256 + (kc) + c * 8, &smB[buf][p * 8]);         \
    }                                                                            \
  }

#define COMPUTE(buf)                                                             \
  {                                                                              \
    _Pragma("unroll") for (int h = 0; h < 2; ++h) {                              \
      short8 af[4], bfr[4];                                                      \
      int cc = h * 4 + lk;                                                       \
      _Pragma("unroll") for (int fm = 0; fm < 4; ++fm) {                         \
        int row = wr * 64 + fm * 16 + lr;                                        \
        af[fm] = *(const short8*)&smA[buf][row * 64 + ((cc ^ (row & 7)) << 3)];  \
      }                                                                          \
      _Pragma("unroll") for (int fn = 0; fn < 4; ++fn) {                         \
        int row = wc * 64 + fn * 16 + lr;                                        \
        bfr[fn] = *(const short8*)&smB[buf][row * 64 + ((cc ^ (row & 7)) << 3)]; \
      }                                                                          \
      _Pragma("unroll") for (int fm = 0; fm < 4; ++fm)                           \
        _Pragma("unroll") for (int fn = 0; fn < 4; ++fn)                         \
          acc[fm][fn] = __builtin_amdgcn_mfma_f32_16x16x32_bf16(                 \
              bfr[fn], af[fm], acc[fm][fn], 0, 0, 0);                            \
    }                                                                            \
  }

  STAGE(0, 0);
  __syncthreads();
  STAGE(1, 64);
  COMPUTE(0);
  __syncthreads();
  STAGE(0, 128);
  COMPUTE(1);
  __syncthreads();
  STAGE(1, 192);
  COMPUTE(0);
  __syncthreads();
  COMPUTE(1);
#undef STAGE
#undef COMPUTE

  const float* bias = (nbase < 256) ? (bias0 + nbase) : (bias1 + (nbase - 256));
#pragma unroll
  for (int fm = 0; fm < 4; ++fm) {
    int m = m0 + wr * 64 + fm * 16 + lr;
    if (m >= M) continue;
#pragma unroll
    for (int fn = 0; fn < 4; ++fn) {
      int lc = wc * 64 + fn * 16 + lk * 4;
      float4 bv = *(const float4*)(bias + lc);
      ushort4 ov;
      ov.x = f2b(acc[fm][fn][0] + bv.x);
      ov.y = f2b(acc[fm][fn][1] + bv.y);
      ov.z = f2b(acc[fm][fn][2] + bv.z);
      ov.w = f2b(acc[fm][fn][3] + bv.w);
      *(ushort4*)(Cout + (size_t)m * LDC3 + nbase + lc) = ov;
    }
  }
}

// -------- fused gather + softmax(17) + threshold + context + W_red GEMM ---------
// 4 nodes per block (1 per wave). After computing its ctx row, each wave stages it
// to LDS (bf16); one barrier; then each wave computes a 16-col tile of the final
// 4x64 output via 8 MFMA with W_red fragments read straight from global (L2-hot).
__global__ __launch_bounds__(256) void gather_kernel(
    const bfu* __restrict__ C3, const float* __restrict__ coords,
    const int* __restrict__ col, const float* __restrict__ bmix,
    const bfu* __restrict__ Wred, const float* __restrict__ bred,
    float* __restrict__ out) {
  __shared__ bfu cstage[16][264];   // rows 0-3 valid; +8 pad kills bank conflicts
  const float L2E = 1.4426950408889634f;
  int lane = threadIdx.x & 63;
  int w = threadIdx.x >> 6;
  int i0 = blockIdx.x << 2;
  int i = i0 + w;
  float beta = bmix[0];

  int ck = col[i * KK + (lane & 15)];
  float2 ci = ((const float2*)coords)[i];
  float2 cn = ((const float2*)coords)[ck];
  float dx = ci.x - cn.x, dy = ci.y - cn.y;
  float dwv = fexp2((-2.0f * L2E / (50.0f + 1e-8f)) * sqrtf(dx * dx + dy * dy)) * L2E;

  int d = lane << 2;
  const bfu* rowi = C3 + (size_t)i * LDC3;
  ushort4 sv = *(const ushort4*)(rowi + d);
  float4 e0 = make_float4(fexp2(L2E * b2f(sv.x)), fexp2(L2E * b2f(sv.y)),
                          fexp2(L2E * b2f(sv.z)), fexp2(L2E * b2f(sv.w)));
  float4 Z = e0;
  float4 ef[KK];
  ushort4 tn[KK];
#pragma unroll
  for (int k = 0; k < KK; ++k) {
    int cc = __shfl(ck, k, 64);
    float ww = __shfl(dwv, k, 64);
    const bfu* rowc = C3 + (size_t)cc * LDC3;
    ushort4 uv = *(const ushort4*)(rowc + 256 + d);
    tn[k] = *(const ushort4*)(rowc + 512 + d);
    float4 e = make_float4(fexp2(ww * b2f(uv.x)), fexp2(ww * b2f(uv.y)),
                           fexp2(ww * b2f(uv.z)), fexp2(ww * b2f(uv.w)));
    ef[k] = e;
    Z.x += e.x; Z.y += e.y; Z.z += e.z; Z.w += e.w;
  }
  // weight e/Z >= 0.01  <=>  e >= 0.01*Z (all positive)
  float4 thr = make_float4(0.01f * Z.x, 0.01f * Z.y, 0.01f * Z.z, 0.01f * Z.w);
  ushort4 tv = *(const ushort4*)(rowi + 512 + d);
  float ob = 1.0f - beta;
  float4 ns = make_float4(0.f, 0.f, 0.f, 0.f);
#pragma unroll
  for (int k = 0; k < KK; ++k) {
    float ex = (ef[k].x >= thr.x) ? ef[k].x : 0.f;
    float ey = (ef[k].y >= thr.y) ? ef[k].y : 0.f;
    float ez = (ef[k].z >= thr.z) ? ef[k].z : 0.f;
    float ew = (ef[k].w >= thr.w) ? ef[k].w : 0.f;
    ns.x += ex * b2f(tn[k].x); ns.y += ey * b2f(tn[k].y);
    ns.z += ez * b2f(tn[k].z); ns.w += ew * b2f(tn[k].w);
  }
  float s0x = (e0.x >= thr.x) ? e0.x : 0.f;
  float s0y = (e0.y >= thr.y) ? e0.y : 0.f;
  float s0z = (e0.z >= thr.z) ? e0.z : 0.f;
  float s0w = (e0.w >= thr.w) ? e0.w : 0.f;
  float4 iz = make_float4(frcp(Z.x), frcp(Z.y), frcp(Z.z), frcp(Z.w));
  ushort4 cb;
  cb.x = f2b((beta * s0x * b2f(tv.x) + ob * ns.x) * iz.x);
  cb.y = f2b((beta * s0y * b2f(tv.y) + ob * ns.y) * iz.y);
  cb.z = f2b((beta * s0z * b2f(tv.z) + ob * ns.z) * iz.z);
  cb.w = f2b((beta * s0w * b2f(tv.w) + ob * ns.w) * iz.w);
  *(ushort4*)&cstage[w][d] = cb;
  __syncthreads();

  // mini-GEMM: out[i0+r][w*16+n] = ctx[r][:] . Wred[w*16+n][:]  (r=0..3 valid)
  int lr16 = lane & 15, lk4 = lane >> 4;
  const bfu* wrow = Wred + (size_t)(w * 16 + lr16) * 256 + (lk4 << 3);
  f32x4 racc = (f32x4){0.f, 0.f, 0.f, 0.f};
#pragma unroll
  for (int ks = 0; ks < 8; ++ks) {
    short8 av = *(const short8*)&cstage[lr16][ks * 32 + (lk4 << 3)];
    short8 bv = *(const short8*)(wrow + ks * 32);
    racc = __builtin_amdgcn_mfma_f32_16x16x32_bf16(av, bv, racc, 0, 0, 0);
  }
  // D layout: row=(lane>>4)*4+q, col=lane&15 -> lanes 0-15 hold rows 0-3
  if (lane < 16) {
    float bb = bred[w * 16 + lane];
#pragma unroll
    for (int q = 0; q < 4; ++q) {
      float vv = racc[q] + bb;
      vv = (vv > 0.f) ? vv : 0.01f * vv;
      vv = (vv > 0.f) ? vv : 0.01f * vv;
      out[(size_t)(i0 + q) * 64 + w * 16 + lane] = vv;
    }
  }
}

extern "C" void kernel_launch(void* const* d_in, const int* in_sizes, int n_in,
                              void* d_out, int out_size, void* d_ws, size_t ws_size,
                              hipStream_t stream) {
  (void)in_sizes; (void)n_in; (void)out_size; (void)ws_size;
  const float* x       = (const float*)d_in[0];
  const float* coords  = (const float*)d_in[1];
  const float* gamma   = (const float*)d_in[2];
  const float* beta_ln = (const float*)d_in[3];
  const float* W_self  = (const float*)d_in[4];
  const float* b_self  = (const float*)d_in[5];
  const float* W_nei   = (const float*)d_in[6];
  const float* b_nei   = (const float*)d_in[7];
  const float* W_red   = (const float*)d_in[8];
  const float* b_red   = (const float*)d_in[9];
  const float* bmix    = (const float*)d_in[10];
  const int*   edge    = (const int*)d_in[11];
  const int*   col     = edge + (size_t)NN * KK;

  // workspace (20096 rows so last-tile OOB reads stay in-bounds & harmless)
  bfu* C3    = (bfu*)d_ws;                              // 20096*768*2 = 30,867,456
  bfu* Wcat  = (bfu*)((char*)d_ws + 30867456);          // 512*256*2   =    262,144
  bfu* Wredb = (bfu*)((char*)d_ws + 31129600);          //  64*256*2   =     32,768

  prep_kernel<<<5576, 256, 0, stream>>>(x, gamma, beta_ln, W_self, W_nei, W_red,
                                        C3, Wcat, Wredb);
  gemm_kernel<<<dim3(157, 4), 256, 0, stream>>>(
      C3 + 512, Wcat, b_self, b_nei, C3, NN);
  gather_kernel<<<5000, 256, 0, stream>>>(C3, coords, col, bmix, Wredb, b_red,
                                          (float*)d_out);
}

// Round 14
// 158.172 us; speedup vs baseline: 1.0977x; 1.0170x over previous
//
#include <hip/hip_runtime.h>
#include <cmath>

#define NN 20000
#define DD 256
#define KK 16
#define LDC3 768   // C3 row: [s 0..255][u 256..511][t 512..767]

typedef __attribute__((ext_vector_type(8))) short short8;
typedef __attribute__((ext_vector_type(4))) float f32x4;
typedef unsigned int u32;
typedef unsigned short bfu;

__device__ __forceinline__ float b2f(bfu u) {
  union { u32 i; float f; } v; v.i = ((u32)u) << 16; return v.f;
}
__device__ __forceinline__ bfu f2b(float f) {
  u32 u = __float_as_uint(f);
  u = (u + 0x7fff + ((u >> 16) & 1)) >> 16;
  return (bfu)u;
}
__device__ __forceinline__ float wave_sum(float v) {
#pragma unroll
  for (int m = 32; m; m >>= 1) v += __shfl_xor(v, m, 64);
  return v;
}
__device__ __forceinline__ void gl_lds16(const void* g, void* l) {
  __builtin_amdgcn_global_load_lds((const __attribute__((address_space(1))) u32*)g,
                                   (__attribute__((address_space(3))) u32*)l, 16, 0, 0);
}
__device__ __forceinline__ float fexp2(float x) { return __builtin_amdgcn_exp2f(x); }
__device__ __forceinline__ float frcp(float x)  { return __builtin_amdgcn_rcpf(x); }
__device__ __forceinline__ float rdlanef(float v, int l) {
  return __int_as_float(__builtin_amdgcn_readlane(__float_as_int(v), l));
}

// -------- prep: LayerNorm (blocks 0..4999) + weight f32->bf16 (blocks 5000+) -----
__global__ __launch_bounds__(256) void prep_kernel(
    const float* __restrict__ x, const float* __restrict__ g,
    const float* __restrict__ b, const float* __restrict__ Wself,
    const float* __restrict__ Wnei, const float* __restrict__ Wred,
    bfu* __restrict__ C3, bfu* __restrict__ Wcat, bfu* __restrict__ Wredb) {
  int bid = blockIdx.x;
  if (bid < 5000) {
    int lane = threadIdx.x & 63;
    int row = (bid << 2) + (threadIdx.x >> 6);
    float4 v = ((const float4*)(x + (size_t)row * DD))[lane];
    float mean = wave_sum(v.x + v.y + v.z + v.w) * (1.0f / 256.0f);
    float4 d = make_float4(v.x - mean, v.y - mean, v.z - mean, v.w - mean);
    float var = wave_sum(d.x * d.x + d.y * d.y + d.z * d.z + d.w * d.w) * (1.0f / 256.0f);
    float rstd = 1.0f / sqrtf(var + 1e-5f);
    float4 g4 = ((const float4*)g)[lane];
    float4 b4 = ((const float4*)b)[lane];
    ushort4 ov;
    ov.x = f2b(d.x * rstd * g4.x + b4.x);
    ov.y = f2b(d.y * rstd * g4.y + b4.y);
    ov.z = f2b(d.z * rstd * g4.z + b4.z);
    ov.w = f2b(d.w * rstd * g4.w + b4.w);
    *(ushort4*)(C3 + (size_t)row * LDC3 + 512 + (lane << 2)) = ov;
  } else {
    int idx = (bid - 5000) * 256 + threadIdx.x;
    if (idx < 65536) Wcat[idx] = f2b(Wself[idx]);
    else if (idx < 131072) Wcat[idx] = f2b(Wnei[idx - 65536]);
    else if (idx < 147456) Wredb[idx - 131072] = f2b(Wred[idx - 131072]);
  }
}

// -------- bf16 MFMA GEMM: r5 dbuf structure + bijective XCD swizzle (by-fast) ----
// Virtual wgid orders (m,by) pairs so each XCD gets contiguous by-groups: the 4
// by-tiles sharing an A-panel run on ONE XCD -> A re-reads become L2 hits.
__global__ __launch_bounds__(256) void gemm_kernel(
    const bfu* __restrict__ A, const bfu* __restrict__ Bw,
    const float* __restrict__ bias0, const float* __restrict__ bias1,
    bfu* __restrict__ Cout, int M) {
  __shared__ bfu smA[2][128 * 64];
  __shared__ bfu smB[2][128 * 64];
  int orig = blockIdx.x;                    // 628 blocks
  int xcd = orig & 7;
  int base = (xcd < 4) ? xcd * 79 : 316 + (xcd - 4) * 78;   // q=78, r=4 (m204)
  int wgid = base + (orig >> 3);
  int m0 = (wgid >> 2) * 128;
  int nbase = (wgid & 3) * 128;
  int tid = threadIdx.x, lane = tid & 63, wid = tid >> 6;
  const bfu* Bt = Bw + (size_t)nbase * 256;
  int wr = wid >> 1, wc = wid & 1;
  int lr = lane & 15, lk = lane >> 4;

  f32x4 acc[4][4];
#pragma unroll
  for (int i = 0; i < 4; ++i)
#pragma unroll
    for (int j = 0; j < 4; ++j) acc[i][j] = (f32x4){0.f, 0.f, 0.f, 0.f};

#define STAGE(buf, kc)                                                           \
  {                                                                              \
    _Pragma("unroll") for (int i = 0; i < 4; ++i) {                              \
      int p = tid + 256 * i; int row = p >> 3; int c = (p & 7) ^ (row & 7);      \
      gl_lds16(A + (size_t)(m0 + row) * LDC3 + (kc) + c * 8, &smA[buf][p * 8]);  \
    }                                                                            \
    _Pragma("unroll") for (int i = 0; i < 4; ++i) {                              \
      int p = tid + 256 * i; int row = p >> 3; int c = (p & 7) ^ (row & 7);      \
      gl_lds16(Bt + (size_t)row * 256 + (kc) + c * 8, &smB[buf][p * 8]);         \
    }                                                                            \
  }

#define COMPUTE(buf)                                                             \
  {                                                                              \
    _Pragma("unroll") for (int h = 0; h < 2; ++h) {                              \
      short8 af[4], bfr[4];                                                      \
      int cc = h * 4 + lk;                                                       \
      _Pragma("unroll") for (int fm = 0; fm < 4; ++fm) {                         \
        int row = wr * 64 + fm * 16 + lr;                                        \
        af[fm] = *(const short8*)&smA[buf][row * 64 + ((cc ^ (row & 7)) << 3)];  \
      }                                                                          \
      _Pragma("unroll") for (int fn = 0; fn < 4; ++fn) {                         \
        int row = wc * 64 + fn * 16 + lr;                                        \
        bfr[fn] = *(const short8*)&smB[buf][row * 64 + ((cc ^ (row & 7)) << 3)]; \
      }                                                                          \
      _Pragma("unroll") for (int fm = 0; fm < 4; ++fm)                           \
        _Pragma("unroll") for (int fn = 0; fn < 4; ++fn)                         \
          acc[fm][fn] = __builtin_amdgcn_mfma_f32_16x16x32_bf16(                 \
              bfr[fn], af[fm], acc[fm][fn], 0, 0, 0);                            \
    }                                                                            \
  }

  STAGE(0, 0);
  __syncthreads();
  STAGE(1, 64);
  COMPUTE(0);
  __syncthreads();
  STAGE(0, 128);
  COMPUTE(1);
  __syncthreads();
  STAGE(1, 192);
  COMPUTE(0);
  __syncthreads();
  COMPUTE(1);
#undef STAGE
#undef COMPUTE

  const float* bias = (nbase < 256) ? (bias0 + nbase) : (bias1 + (nbase - 256));
#pragma unroll
  for (int fm = 0; fm < 4; ++fm) {
    int m = m0 + wr * 64 + fm * 16 + lr;
    if (m >= M) continue;
#pragma unroll
    for (int fn = 0; fn < 4; ++fn) {
      int lc = wc * 64 + fn * 16 + lk * 4;
      float4 bv = *(const float4*)(bias + lc);
      ushort4 ov;
      ov.x = f2b(acc[fm][fn][0] + bv.x);
      ov.y = f2b(acc[fm][fn][1] + bv.y);
      ov.z = f2b(acc[fm][fn][2] + bv.z);
      ov.w = f2b(acc[fm][fn][3] + bv.w);
      *(ushort4*)(Cout + (size_t)m * LDC3 + nbase + lc) = ov;
    }
  }
}

// -------- fused gather + softmax(17) + threshold + context + W_red GEMM ---------
// MLP-first restructure: all 32 neighbor loads issued up front via readlane/SGPR
// base addressing (uniform row base + per-lane 32b offset), destinations in regs;
// exp recomputed in pass 2 instead of storing ef[16] (saves 64 VGPRs).
__global__ __launch_bounds__(256) void gather_kernel(
    const bfu* __restrict__ C3, const float* __restrict__ coords,
    const int* __restrict__ col, const float* __restrict__ bmix,
    const bfu* __restrict__ Wred, const float* __restrict__ bred,
    float* __restrict__ out) {
  __shared__ bfu cstage[16][264];
  const float L2E = 1.4426950408889634f;
  int lane = threadIdx.x & 63;
  int w = threadIdx.x >> 6;
  int i0 = blockIdx.x << 2;
  int i = i0 + w;
  float beta = bmix[0];

  int ck = col[i * KK + (lane & 15)];
  float2 ci = ((const float2*)coords)[i];
  float2 cn = ((const float2*)coords)[ck];
  float dx = ci.x - cn.x, dy = ci.y - cn.y;
  float dwv = fexp2((-2.0f * L2E / (50.0f + 1e-8f)) * sqrtf(dx * dx + dy * dy)) * L2E;

  int d = lane << 2;
  const bfu* rowi = C3 + (size_t)i * LDC3;
  ushort4 sv = *(const ushort4*)(rowi + d);
  ushort4 tv = *(const ushort4*)(rowi + 512 + d);

  // ---- issue all 32 neighbor loads (SGPR base per k, shared v-offset) ----
  ushort4 uvr[KK], tnr[KK];
#pragma unroll
  for (int k = 0; k < KK; ++k) {
    int cc = __builtin_amdgcn_readlane(ck, k);        // uniform -> SGPR
    const bfu* rowc = C3 + (size_t)cc * LDC3;
    uvr[k] = *(const ushort4*)(rowc + 256 + d);
    tnr[k] = *(const ushort4*)(rowc + 512 + d);
  }

  // ---- pass 1: Z ----
  float4 e0 = make_float4(fexp2(L2E * b2f(sv.x)), fexp2(L2E * b2f(sv.y)),
                          fexp2(L2E * b2f(sv.z)), fexp2(L2E * b2f(sv.w)));
  float4 Z = e0;
#pragma unroll
  for (int k = 0; k < KK; ++k) {
    float sw = rdlanef(dwv, k);
    Z.x += fexp2(sw * b2f(uvr[k].x));
    Z.y += fexp2(sw * b2f(uvr[k].y));
    Z.z += fexp2(sw * b2f(uvr[k].z));
    Z.w += fexp2(sw * b2f(uvr[k].w));
  }
  // threshold on weight e/Z >= 0.01  <=>  e >= 0.01*Z (all positive)
  float4 thr = make_float4(0.01f * Z.x, 0.01f * Z.y, 0.01f * Z.z, 0.01f * Z.w);

  // ---- pass 2: recompute e (bit-identical), threshold, accumulate ns ----
  float ob = 1.0f - beta;
  float4 ns = make_float4(0.f, 0.f, 0.f, 0.f);
#pragma unroll
  for (int k = 0; k < KK; ++k) {
    float sw = rdlanef(dwv, k);
    float ex = fexp2(sw * b2f(uvr[k].x));
    float ey = fexp2(sw * b2f(uvr[k].y));
    float ez = fexp2(sw * b2f(uvr[k].z));
    float ew = fexp2(sw * b2f(uvr[k].w));
    ns.x += ((ex >= thr.x) ? ex : 0.f) * b2f(tnr[k].x);
    ns.y += ((ey >= thr.y) ? ey : 0.f) * b2f(tnr[k].y);
    ns.z += ((ez >= thr.z) ? ez : 0.f) * b2f(tnr[k].z);
    ns.w += ((ew >= thr.w) ? ew : 0.f) * b2f(tnr[k].w);
  }
  float s0x = (e0.x >= thr.x) ? e0.x : 0.f;
  float s0y = (e0.y >= thr.y) ? e0.y : 0.f;
  float s0z = (e0.z >= thr.z) ? e0.z : 0.f;
  float s0w = (e0.w >= thr.w) ? e0.w : 0.f;
  float4 iz = make_float4(frcp(Z.x), frcp(Z.y), frcp(Z.z), frcp(Z.w));
  ushort4 cb;
  cb.x = f2b((beta * s0x * b2f(tv.x) + ob * ns.x) * iz.x);
  cb.y = f2b((beta * s0y * b2f(tv.y) + ob * ns.y) * iz.y);
  cb.z = f2b((beta * s0z * b2f(tv.z) + ob * ns.z) * iz.z);
  cb.w = f2b((beta * s0w * b2f(tv.w) + ob * ns.w) * iz.w);
  *(ushort4*)&cstage[w][d] = cb;
  __syncthreads();

  // mini-GEMM: out[i0+r][w*16+n] = ctx[r][:] . Wred[w*16+n][:]  (r=0..3 valid)
  int lr16 = lane & 15, lk4 = lane >> 4;
  const bfu* wrow = Wred + (size_t)(w * 16 + lr16) * 256 + (lk4 << 3);
  f32x4 racc = (f32x4){0.f, 0.f, 0.f, 0.f};
#pragma unroll
  for (int ks = 0; ks < 8; ++ks) {
    short8 av = *(const short8*)&cstage[lr16][ks * 32 + (lk4 << 3)];
    short8 bv = *(const short8*)(wrow + ks * 32);
    racc = __builtin_amdgcn_mfma_f32_16x16x32_bf16(av, bv, racc, 0, 0, 0);
  }
  if (lane < 16) {
    float bb = bred[w * 16 + lane];
#pragma unroll
    for (int q = 0; q < 4; ++q) {
      float vv = racc[q] + bb;
      vv = (vv > 0.f) ? vv : 0.01f * vv;
      vv = (vv > 0.f) ? vv : 0.01f * vv;
      out[(size_t)(i0 + q) * 64 + w * 16 + lane] = vv;
    }
  }
}

extern "C" void kernel_launch(void* const* d_in, const int* in_sizes, int n_in,
                              void* d_out, int out_size, void* d_ws, size_t ws_size,
                              hipStream_t stream) {
  (void)in_sizes; (void)n_in; (void)out_size; (void)ws_size;
  const float* x       = (const float*)d_in[0];
  const float* coords  = (const float*)d_in[1];
  const float* gamma   = (const float*)d_in[2];
  const float* beta_ln = (const float*)d_in[3];
  const float* W_self  = (const float*)d_in[4];
  const float* b_self  = (const float*)d_in[5];
  const float* W_nei   = (const float*)d_in[6];
  const float* b_nei   = (const float*)d_in[7];
  const float* W_red   = (const float*)d_in[8];
  const float* b_red   = (const float*)d_in[9];
  const float* bmix    = (const float*)d_in[10];
  const int*   edge    = (const int*)d_in[11];
  const int*   col     = edge + (size_t)NN * KK;

  // workspace (20096 rows so last-tile OOB reads stay in-bounds & harmless)
  bfu* C3    = (bfu*)d_ws;                              // 20096*768*2 = 30,867,456
  bfu* Wcat  = (bfu*)((char*)d_ws + 30867456);          // 512*256*2   =    262,144
  bfu* Wredb = (bfu*)((char*)d_ws + 31129600);          //  64*256*2   =     32,768

  prep_kernel<<<5576, 256, 0, stream>>>(x, gamma, beta_ln, W_self, W_nei, W_red,
                                        C3, Wcat, Wredb);
  gemm_kernel<<<dim3(628), 256, 0, stream>>>(
      C3 + 512, Wcat, b_self, b_nei, C3, NN);
  gather_kernel<<<5000, 256, 0, stream>>>(C3, coords, col, bmix, Wredb, b_red,
                                          (float*)d_out);
}